// Round 5
// baseline (2017.823 us; speedup 1.0000x reference)
//
#include <hip/hip_runtime.h>

#define NN 8192
#define CIN 32
#define COUT 64
#define KF 5
#define NT 512          // i-tiles (16 rows each)
#define PITERS 16       // K-iters per wave: 16 * 32 = 512; 8 waves * 512 * 2 halves = 8192

typedef __attribute__((ext_vector_type(8))) short bf16x8_t;
typedef __attribute__((ext_vector_type(4))) float f32x4_t;

// fp32 -> bf16 RNE
__device__ __forceinline__ short f2bf(float f) {
    unsigned u = __builtin_bit_cast(unsigned, f);
    unsigned r = (u + 0x7FFFu + ((u >> 16) & 1u)) >> 16;
    return (short)(unsigned short)r;
}

__device__ __forceinline__ bf16x8_t cvt8(float4 a, float4 b) {
    bf16x8_t v;
    v[0] = f2bf(a.x); v[1] = f2bf(a.y); v[2] = f2bf(a.z); v[3] = f2bf(a.w);
    v[4] = f2bf(b.x); v[5] = f2bf(b.y); v[6] = f2bf(b.z); v[7] = f2bf(b.w);
    return v;
}

// D layout (m89, validated R1-R4): col=lane&15 -> i, row=(lane>>4)*4+reg -> c
__device__ __forceinline__ void stash_partials(float* red, int wave, int g, int r,
                                               const f32x4_t& acc0, const f32x4_t& acc1) {
    const int base = wave * 512 + g * 64 + r;
#pragma unroll
    for (int t = 0; t < 4; ++t) {
        red[base + t * 16]       = acc0[t];
        red[base + t * 16 + 256] = acc1[t];
    }
}

// After stash: sum the 8 wave partials for column `tid` (c=tid>>4, il=tid&15)
__device__ __forceinline__ float reduce8(const float* red, int tid) {
    float s = red[tid];
#pragma unroll
    for (int w = 1; w < 8; ++w) s += red[w * 512 + tid];
    return s;
}

// Last-block ticket: deterministic output (combine order fixed); atomic only
// selects which block performs it. Standard release/acquire fence pattern.
__device__ __forceinline__ bool ticket_last(unsigned* cnt_t, int tid, int* flagLds) {
    __threadfence();
    __syncthreads();
    if (tid == 0) *flagLds = (atomicAdd(cnt_t, 1u) == 1u) ? 1 : 0;
    __syncthreads();
    if (*flagLds == 0) return false;
    __threadfence();
    return true;
}

// ---- Pass 1: reads fp32 L (inline cvt, stash bf16 Lb), A = bf16(x) inline.
// Grid 1024 = tile t (b>>1) x K-half h (b&1). 8 waves, wave K-range = 512.
__global__ __launch_bounds__(512, 4) void pass1_kernel(
    const float* __restrict__ L, const float* __restrict__ x,
    short* __restrict__ Lb, float* __restrict__ part, unsigned* __restrict__ cnt,
    float* __restrict__ Tf1, short* __restrict__ Tb1)
{
    __shared__ float red[8 * 512];
    __shared__ int flagLds;
    const int tid = threadIdx.x, wave = tid >> 6, lane = tid & 63;
    const int g = lane >> 4, r = lane & 15;
    const int t = blockIdx.x >> 1, h = blockIdx.x & 1;
    const int i0 = t * 16;
    const int jb = h * 4096 + wave * 512 + g * 8;

    const float* Lrow = L + (size_t)(i0 + r) * NN;
    short* LbRow = Lb + (size_t)(i0 + r) * NN;
    const float* X0 = x + (size_t)r * NN;
    const float* X1 = x + (size_t)(r + 16) * NN;

    f32x4_t acc0 = {0.f, 0.f, 0.f, 0.f};
    f32x4_t acc1 = {0.f, 0.f, 0.f, 0.f};

    float4 lc0 = *(const float4*)(Lrow + jb);
    float4 lc1 = *(const float4*)(Lrow + jb + 4);
    float4 x0c0 = *(const float4*)(X0 + jb);
    float4 x0c1 = *(const float4*)(X0 + jb + 4);
    float4 x1c0 = *(const float4*)(X1 + jb);
    float4 x1c1 = *(const float4*)(X1 + jb + 4);
    for (int it = 0; it < PITERS; ++it) {
        const int jn = jb + ((it + 1) & (PITERS - 1)) * 32;   // wraps on last (in-bounds)
        float4 ln0 = *(const float4*)(Lrow + jn);
        float4 ln1 = *(const float4*)(Lrow + jn + 4);
        float4 x0n0 = *(const float4*)(X0 + jn);
        float4 x0n1 = *(const float4*)(X0 + jn + 4);
        float4 x1n0 = *(const float4*)(X1 + jn);
        float4 x1n1 = *(const float4*)(X1 + jn + 4);
        bf16x8_t bfr = cvt8(lc0, lc1);
        *(bf16x8_t*)(LbRow + jb + it * 32) = bfr;
        acc0 = __builtin_amdgcn_mfma_f32_16x16x32_bf16(cvt8(x0c0, x0c1), bfr, acc0, 0, 0, 0);
        acc1 = __builtin_amdgcn_mfma_f32_16x16x32_bf16(cvt8(x1c0, x1c1), bfr, acc1, 0, 0, 0);
        lc0 = ln0; lc1 = ln1; x0c0 = x0n0; x0c1 = x0n1; x1c0 = x1n0; x1c1 = x1n1;
    }

    stash_partials(red, wave, g, r, acc0, acc1);
    __syncthreads();
    const int c = tid >> 4, il = tid & 15;
    part[(size_t)h * CIN * NN + (size_t)c * NN + i0 + il] = reduce8(red, tid);

    if (!ticket_last(cnt + t, tid, &flagLds)) return;
    const size_t off = (size_t)c * NN + i0 + il;
    float val = part[off] + part[(size_t)CIN * NN + off];
    Tf1[off] = val;
    Tb1[off] = f2bf(val);
}

// ---- Mid passes (2,3): T_next = 2*(Tcur @ L^T) - Tprev; bf16 Lb reads.
__global__ __launch_bounds__(512, 8) void passmid_kernel(
    const short* __restrict__ Lb, const short* __restrict__ A,
    const float* __restrict__ Tprev, float* __restrict__ part,
    unsigned* __restrict__ cnt, float* __restrict__ Tf, short* __restrict__ Tb)
{
    __shared__ float red[8 * 512];
    __shared__ int flagLds;
    const int tid = threadIdx.x, wave = tid >> 6, lane = tid & 63;
    const int g = lane >> 4, r = lane & 15;
    const int t = blockIdx.x >> 1, h = blockIdx.x & 1;
    const int i0 = t * 16;
    const int jb = h * 4096 + wave * 512 + g * 8;

    const short* Lrow = Lb + (size_t)(i0 + r) * NN;
    const short* A0 = A + (size_t)r * NN;
    const short* A1 = A + (size_t)(r + 16) * NN;

    f32x4_t acc0 = {0.f, 0.f, 0.f, 0.f};
    f32x4_t acc1 = {0.f, 0.f, 0.f, 0.f};

    bf16x8_t bc  = *(const bf16x8_t*)(Lrow + jb);
    bf16x8_t ac0 = *(const bf16x8_t*)(A0 + jb);
    bf16x8_t ac1 = *(const bf16x8_t*)(A1 + jb);
    for (int it = 0; it < PITERS; ++it) {
        const int jn = jb + ((it + 1) & (PITERS - 1)) * 32;
        bf16x8_t bn  = *(const bf16x8_t*)(Lrow + jn);
        bf16x8_t an0 = *(const bf16x8_t*)(A0 + jn);
        bf16x8_t an1 = *(const bf16x8_t*)(A1 + jn);
        acc0 = __builtin_amdgcn_mfma_f32_16x16x32_bf16(ac0, bc, acc0, 0, 0, 0);
        acc1 = __builtin_amdgcn_mfma_f32_16x16x32_bf16(ac1, bc, acc1, 0, 0, 0);
        bc = bn; ac0 = an0; ac1 = an1;
    }

    stash_partials(red, wave, g, r, acc0, acc1);
    __syncthreads();
    const int c = tid >> 4, il = tid & 15;
    part[(size_t)h * CIN * NN + (size_t)c * NN + i0 + il] = reduce8(red, tid);

    if (!ticket_last(cnt + t, tid, &flagLds)) return;
    const size_t off = (size_t)c * NN + i0 + il;
    float val = 2.0f * (part[off] + part[(size_t)CIN * NN + off]) - Tprev[off];
    Tf[off] = val;
    Tb[off] = f2bf(val);
}

// ---- Pass 4 + fused final einsum (T4 never hits global):
__global__ __launch_bounds__(512, 8) void pass4_kernel(
    const short* __restrict__ Lb, const short* __restrict__ A,
    const float* __restrict__ Tf2, const float* __restrict__ x,
    const float* __restrict__ Tf1, const float* __restrict__ Tf3,
    const float* __restrict__ theta, const float* __restrict__ bias,
    float* __restrict__ part, unsigned* __restrict__ cnt, float* __restrict__ y)
{
    __shared__ float red[8 * 512];
    __shared__ int flagLds;
    const int tid = threadIdx.x, wave = tid >> 6, lane = tid & 63;
    const int g = lane >> 4, r = lane & 15;
    const int t = blockIdx.x >> 1, h = blockIdx.x & 1;
    const int i0 = t * 16;
    const int jb = h * 4096 + wave * 512 + g * 8;

    const short* Lrow = Lb + (size_t)(i0 + r) * NN;
    const short* A0 = A + (size_t)r * NN;
    const short* A1 = A + (size_t)(r + 16) * NN;

    f32x4_t acc0 = {0.f, 0.f, 0.f, 0.f};
    f32x4_t acc1 = {0.f, 0.f, 0.f, 0.f};

    bf16x8_t bc  = *(const bf16x8_t*)(Lrow + jb);
    bf16x8_t ac0 = *(const bf16x8_t*)(A0 + jb);
    bf16x8_t ac1 = *(const bf16x8_t*)(A1 + jb);
    for (int it = 0; it < PITERS; ++it) {
        const int jn = jb + ((it + 1) & (PITERS - 1)) * 32;
        bf16x8_t bn  = *(const bf16x8_t*)(Lrow + jn);
        bf16x8_t an0 = *(const bf16x8_t*)(A0 + jn);
        bf16x8_t an1 = *(const bf16x8_t*)(A1 + jn);
        acc0 = __builtin_amdgcn_mfma_f32_16x16x32_bf16(ac0, bc, acc0, 0, 0, 0);
        acc1 = __builtin_amdgcn_mfma_f32_16x16x32_bf16(ac1, bc, acc1, 0, 0, 0);
        bc = bn; ac0 = an0; ac1 = an1;
    }

    stash_partials(red, wave, g, r, acc0, acc1);
    __syncthreads();
    const int c = tid >> 4, il = tid & 15;
    part[(size_t)h * CIN * NN + (size_t)c * NN + i0 + il] = reduce8(red, tid);

    if (!ticket_last(cnt + t, tid, &flagLds)) return;

    // T4 for this tile, into LDS (red[tid] == red[c*16+il]; WAR safe: own slot only)
    {
        const size_t off = (size_t)c * NN + i0 + il;
        red[tid] = 2.0f * (part[off] + part[(size_t)CIN * NN + off]) - Tf2[off];
    }
    __syncthreads();

    // einsum: thread -> (o=tid>>4, o+32) x column (i0 + il)
    const int o = tid >> 4;
    float a0 = bias[o], a1 = bias[o + 32];
    for (int cc = 0; cc < CIN; ++cc) {
        const size_t off = (size_t)cc * NN + i0 + il;
        const float t0 = x[off], t1 = Tf1[off], t2 = Tf2[off], t3 = Tf3[off];
        const float t4 = red[cc * 16 + il];
        const float* th0 = theta + ((size_t)o * CIN + cc) * KF;
        const float* th1 = theta + ((size_t)(o + 32) * CIN + cc) * KF;
        a0 += t0 * th0[0] + t1 * th0[1] + t2 * th0[2] + t3 * th0[3] + t4 * th0[4];
        a1 += t0 * th1[0] + t1 * th1[1] + t2 * th1[2] + t3 * th1[3] + t4 * th1[4];
    }
    y[(size_t)o * NN + i0 + il]        = a0;
    y[(size_t)(o + 32) * NN + i0 + il] = a1;
}

extern "C" void kernel_launch(void* const* d_in, const int* in_sizes, int n_in,
                              void* d_out, int out_size, void* d_ws, size_t ws_size,
                              hipStream_t stream) {
    const float* L     = (const float*)d_in[0];
    const float* x     = (const float*)d_in[1];
    const float* theta = (const float*)d_in[2];
    const float* bias  = (const float*)d_in[3];
    float* y = (float*)d_out;

    const size_t TE = (size_t)CIN * NN;
    const size_t LE = (size_t)NN * NN;

    // ws: Lb(128MB) | Tf1..Tf3 (1MB ea) | Tb1..Tb3 (0.5MB ea) | part(2MB) | cnt(8KB)
    short* Lb  = (short*)d_ws;
    float* Tf1 = (float*)(Lb + LE);
    float* Tf2 = Tf1 + TE;
    float* Tf3 = Tf2 + TE;
    short* Tb1 = (short*)(Tf3 + TE);
    short* Tb2 = Tb1 + TE;
    short* Tb3 = Tb2 + TE;
    float* part = (float*)(Tb3 + TE);
    unsigned* cnt = (unsigned*)(part + 2 * TE);

    hipMemsetAsync(cnt, 0, 4 * NT * sizeof(unsigned), stream);
    pass1_kernel<<<2 * NT, 512, 0, stream>>>(L, x, Lb, part, cnt, Tf1, Tb1);
    passmid_kernel<<<2 * NT, 512, 0, stream>>>(Lb, Tb1, x,   part, cnt + NT,     Tf2, Tb2);
    passmid_kernel<<<2 * NT, 512, 0, stream>>>(Lb, Tb2, Tf1, part, cnt + 2 * NT, Tf3, Tb3);
    pass4_kernel<<<2 * NT, 512, 0, stream>>>(Lb, Tb3, Tf2, x, Tf1, Tf3, theta, bias,
                                             part, cnt + 3 * NT, y);
}

// Round 6
// 281.998 us; speedup vs baseline: 7.1554x; 7.1554x over previous
//
#include <hip/hip_runtime.h>

#define NN 8192
#define CIN 32
#define COUT 64
#define KF 5

typedef __attribute__((ext_vector_type(8))) short bf16x8_t;
typedef __attribute__((ext_vector_type(4))) float f32x4_t;

// fp32 -> bf16 RNE
__device__ __forceinline__ short f2bf(float f) {
    unsigned u = __builtin_bit_cast(unsigned, f);
    unsigned r = (u + 0x7FFFu + ((u >> 16) & 1u)) >> 16;
    return (short)(unsigned short)r;
}

__device__ __forceinline__ bf16x8_t cvt8(float4 a, float4 b) {
    bf16x8_t v;
    v[0] = f2bf(a.x); v[1] = f2bf(a.y); v[2] = f2bf(a.z); v[3] = f2bf(a.w);
    v[4] = f2bf(b.x); v[5] = f2bf(b.y); v[6] = f2bf(b.z); v[7] = f2bf(b.w);
    return v;
}

// x fp32 -> bf16 (CIN*NN/4 = 65536 quads; grid 256x256)
__global__ void cvt_kernel(const float* __restrict__ src, short* __restrict__ dst) {
    int idx = blockIdx.x * 256 + threadIdx.x;
    float4 v = reinterpret_cast<const float4*>(src)[idx];
    short4 o;
    o.x = f2bf(v.x); o.y = f2bf(v.y); o.z = f2bf(v.z); o.w = f2bf(v.w);
    reinterpret_cast<short4*>(dst)[idx] = o;
}

// D layout (m89, validated R1-R4): col=lane&15 -> i, row=(lane>>4)*4+reg -> c
__device__ __forceinline__ void stash_partials(float* red, int wave, int g, int r,
                                               const f32x4_t& acc0, const f32x4_t& acc1) {
    const int base = wave * 512 + g * 64 + r;
#pragma unroll
    for (int t = 0; t < 4; ++t) {
        red[base + t * 16]       = acc0[t];
        red[base + t * 16 + 256] = acc1[t];
    }
}

__device__ __forceinline__ float reduce8(const float* red, int tid) {
    float s = red[tid];
#pragma unroll
    for (int w = 1; w < 8; ++w) s += red[w * 512 + tid];
    return s;
}

// ---- Pass 1 (R4-proven): reads fp32 L (inline cvt, stash bf16 Lb), A = Tb0.
// Grid 512; block = 8 waves; i-tile 16; wave w owns K-range [w*1024,(w+1)*1024)
__global__ __launch_bounds__(512, 4) void pass1_kernel(
    const float* __restrict__ L, const short* __restrict__ Tb0,
    short* __restrict__ Lb, float* __restrict__ Tf1, short* __restrict__ Tb1)
{
    __shared__ float red[8 * 512];
    const int tid = threadIdx.x, wave = tid >> 6, lane = tid & 63;
    const int g = lane >> 4, r = lane & 15;
    const int i0 = blockIdx.x * 16;
    const int jb = wave * (NN / 8);

    const float* Lrow = L + (size_t)(i0 + r) * NN;
    short* LbRow = Lb + (size_t)(i0 + r) * NN;
    f32x4_t acc0 = {0.f, 0.f, 0.f, 0.f};
    f32x4_t acc1 = {0.f, 0.f, 0.f, 0.f};
    for (int j = jb; j < jb + NN / 8; j += 32) {
        const int jl = j + g * 8;
        float4 l0 = *reinterpret_cast<const float4*>(Lrow + jl);
        float4 l1 = *reinterpret_cast<const float4*>(Lrow + jl + 4);
        bf16x8_t b = cvt8(l0, l1);
        *reinterpret_cast<bf16x8_t*>(LbRow + jl) = b;
        bf16x8_t a0 = *reinterpret_cast<const bf16x8_t*>(Tb0 + (size_t)r * NN + jl);
        bf16x8_t a1 = *reinterpret_cast<const bf16x8_t*>(Tb0 + (size_t)(r + 16) * NN + jl);
        acc0 = __builtin_amdgcn_mfma_f32_16x16x32_bf16(a0, b, acc0, 0, 0, 0);
        acc1 = __builtin_amdgcn_mfma_f32_16x16x32_bf16(a1, b, acc1, 0, 0, 0);
    }
    stash_partials(red, wave, g, r, acc0, acc1);
    __syncthreads();
    const int c = tid >> 4, il = tid & 15;
    const float val = reduce8(red, tid);
    const size_t off = (size_t)c * NN + i0 + il;
    Tf1[off] = val;
    Tb1[off] = f2bf(val);
}

// ---- Passes 2/3/4 GEMM half: part[h][c][i] = sum_{j in half h} A[c][j]*Lb[i][j]
// Grid 1024 (t = bx>>1, h = bx&1) -> 4 blocks/CU, 32 waves/CU. Plain loop.
__global__ __launch_bounds__(512, 8) void passmid_kernel(
    const short* __restrict__ Lb, const short* __restrict__ A,
    float* __restrict__ part)
{
    __shared__ float red[8 * 512];
    const int tid = threadIdx.x, wave = tid >> 6, lane = tid & 63;
    const int g = lane >> 4, r = lane & 15;
    const int t = blockIdx.x >> 1, h = blockIdx.x & 1;
    const int i0 = t * 16;
    const int jb = h * 4096 + wave * 512;

    const short* Lrow = Lb + (size_t)(i0 + r) * NN;
    const short* A0 = A + (size_t)r * NN;
    const short* A1 = A + (size_t)(r + 16) * NN;

    f32x4_t acc0 = {0.f, 0.f, 0.f, 0.f};
    f32x4_t acc1 = {0.f, 0.f, 0.f, 0.f};
#pragma unroll 4
    for (int it = 0; it < 16; ++it) {
        const int jl = jb + it * 32 + g * 8;
        bf16x8_t b  = *reinterpret_cast<const bf16x8_t*>(Lrow + jl);
        bf16x8_t a0 = *reinterpret_cast<const bf16x8_t*>(A0 + jl);
        bf16x8_t a1 = *reinterpret_cast<const bf16x8_t*>(A1 + jl);
        acc0 = __builtin_amdgcn_mfma_f32_16x16x32_bf16(a0, b, acc0, 0, 0, 0);
        acc1 = __builtin_amdgcn_mfma_f32_16x16x32_bf16(a1, b, acc1, 0, 0, 0);
    }

    stash_partials(red, wave, g, r, acc0, acc1);
    __syncthreads();
    const int c = tid >> 4, il = tid & 15;
    part[(size_t)h * CIN * NN + (size_t)c * NN + i0 + il] = reduce8(red, tid);
}

// ---- Combine for T2/T3: T = 2*(part0+part1) - Tprev; write fp32 + bf16
__global__ __launch_bounds__(256) void combine_kernel(
    const float* __restrict__ part, const float* __restrict__ Tprev,
    float* __restrict__ Tf, short* __restrict__ Tb)
{
    const int idx = blockIdx.x * 256 + threadIdx.x;     // quad index, CIN*NN/4 total
    const float4 p0 = reinterpret_cast<const float4*>(part)[idx];
    const float4 p1 = reinterpret_cast<const float4*>(part + (size_t)CIN * NN)[idx];
    const float4 tp = reinterpret_cast<const float4*>(Tprev)[idx];
    float4 v;
    v.x = 2.f * (p0.x + p1.x) - tp.x;
    v.y = 2.f * (p0.y + p1.y) - tp.y;
    v.z = 2.f * (p0.z + p1.z) - tp.z;
    v.w = 2.f * (p0.w + p1.w) - tp.w;
    reinterpret_cast<float4*>(Tf)[idx] = v;
    short4 b;
    b.x = f2bf(v.x); b.y = f2bf(v.y); b.z = f2bf(v.z); b.w = f2bf(v.w);
    reinterpret_cast<short4*>(Tb)[idx] = b;
}

// ---- Final: T4 = 2*(part0+part1) - T2 computed inline; y = einsum + bias.
// Grid (COUT/2)*NN/256 = 1024; thread -> (o0=2*op, o1) x column i.
__global__ __launch_bounds__(256) void final_kernel(
    const float* __restrict__ x, const float* __restrict__ Tf1,
    const float* __restrict__ Tf2, const float* __restrict__ Tf3,
    const float* __restrict__ part,
    const float* __restrict__ theta, const float* __restrict__ bias,
    float* __restrict__ y)
{
    const long idx = (long)blockIdx.x * 256 + threadIdx.x;
    const int i = (int)(idx & (NN - 1));
    const int op = (int)(idx >> 13);          // block-uniform (32 blocks per op)
    const int o0 = op * 2, o1 = op * 2 + 1;
    float a0 = bias[o0], a1 = bias[o1];
    for (int c = 0; c < CIN; ++c) {
        const size_t off = (size_t)c * NN + i;
        const float t0 = x[off], t1 = Tf1[off], t2 = Tf2[off], t3 = Tf3[off];
        const float t4 = 2.f * (part[off] + part[(size_t)CIN * NN + off]) - t2;
        const float* th0 = theta + ((size_t)o0 * CIN + c) * KF;
        const float* th1 = theta + ((size_t)o1 * CIN + c) * KF;
        a0 += t0 * th0[0] + t1 * th0[1] + t2 * th0[2] + t3 * th0[3] + t4 * th0[4];
        a1 += t0 * th1[0] + t1 * th1[1] + t2 * th1[2] + t3 * th1[3] + t4 * th1[4];
    }
    y[(size_t)o0 * NN + i] = a0;
    y[(size_t)o1 * NN + i] = a1;
}

extern "C" void kernel_launch(void* const* d_in, const int* in_sizes, int n_in,
                              void* d_out, int out_size, void* d_ws, size_t ws_size,
                              hipStream_t stream) {
    const float* L     = (const float*)d_in[0];
    const float* x     = (const float*)d_in[1];
    const float* theta = (const float*)d_in[2];
    const float* bias  = (const float*)d_in[3];
    float* y = (float*)d_out;

    const size_t TE = (size_t)CIN * NN;
    const size_t LE = (size_t)NN * NN;

    // ws: Lb(128MB) | Tf1..Tf3 (1MB ea) | Tb0..Tb3 (0.5MB ea) | part (2MB)
    short* Lb  = (short*)d_ws;
    float* Tf1 = (float*)(Lb + LE);
    float* Tf2 = Tf1 + TE;
    float* Tf3 = Tf2 + TE;
    short* Tb0 = (short*)(Tf3 + TE);
    short* Tb1 = Tb0 + TE;
    short* Tb2 = Tb1 + TE;
    short* Tb3 = Tb2 + TE;
    float* part = (float*)(Tb3 + TE);

    cvt_kernel<<<256, 256, 0, stream>>>(x, Tb0);
    pass1_kernel<<<NN / 16, 512, 0, stream>>>(L, Tb0, Lb, Tf1, Tb1);

    passmid_kernel<<<NN / 8, 512, 0, stream>>>(Lb, Tb1, part);          // T1 @ L^T halves
    combine_kernel<<<TE / 4 / 256, 256, 0, stream>>>(part, x, Tf2, Tb2);   // T2

    passmid_kernel<<<NN / 8, 512, 0, stream>>>(Lb, Tb2, part);          // T2 @ L^T halves
    combine_kernel<<<TE / 4 / 256, 256, 0, stream>>>(part, Tf1, Tf3, Tb3); // T3

    passmid_kernel<<<NN / 8, 512, 0, stream>>>(Lb, Tb3, part);          // T3 @ L^T halves
    final_kernel<<<(COUT / 2) * NN / 256, 256, 0, stream>>>(
        x, Tf1, Tf2, Tf3, part, theta, bias, y);                           // T4 + einsum
}

// Round 7
// 272.175 us; speedup vs baseline: 7.4137x; 1.0361x over previous
//
#include <hip/hip_runtime.h>

#define NN 8192
#define CIN 32
#define COUT 64
#define KF 5

typedef __attribute__((ext_vector_type(8))) short bf16x8_t;
typedef __attribute__((ext_vector_type(4))) float f32x4_t;

// fp32 -> bf16 RNE
__device__ __forceinline__ short f2bf(float f) {
    unsigned u = __builtin_bit_cast(unsigned, f);
    unsigned r = (u + 0x7FFFu + ((u >> 16) & 1u)) >> 16;
    return (short)(unsigned short)r;
}

__device__ __forceinline__ bf16x8_t cvt8(float4 a, float4 b) {
    bf16x8_t v;
    v[0] = f2bf(a.x); v[1] = f2bf(a.y); v[2] = f2bf(a.z); v[3] = f2bf(a.w);
    v[4] = f2bf(b.x); v[5] = f2bf(b.y); v[6] = f2bf(b.z); v[7] = f2bf(b.w);
    return v;
}

// D layout (m89, validated R1-R6): col=lane&15 -> i, row=(lane>>4)*4+reg -> c
__device__ __forceinline__ void stash_partials(float* red, int wave, int g, int r,
                                               const f32x4_t& acc0, const f32x4_t& acc1) {
    const int base = wave * 512 + g * 64 + r;
#pragma unroll
    for (int t = 0; t < 4; ++t) {
        red[base + t * 16]       = acc0[t];
        red[base + t * 16 + 256] = acc1[t];
    }
}

__device__ __forceinline__ float reduce8(const float* red, int tid) {
    float s = red[tid];
#pragma unroll
    for (int w = 1; w < 8; ++w) s += red[w * 512 + tid];
    return s;
}

// ---- Pass 1: reads fp32 L (inline cvt, stash bf16 Lb), A = bf16(x) inline.
// Grid 512; 8 waves; i-tile 16; wave K-range 1024 as two independent 512 streams.
__global__ __launch_bounds__(512, 4) void pass1_kernel(
    const float* __restrict__ L, const float* __restrict__ x,
    short* __restrict__ Lb, float* __restrict__ Tf1, short* __restrict__ Tb1)
{
    __shared__ float red[8 * 512];
    const int tid = threadIdx.x, wave = tid >> 6, lane = tid & 63;
    const int g = lane >> 4, r = lane & 15;
    const int i0 = blockIdx.x * 16;
    const int jb = wave * 1024 + g * 8;

    const float* Lrow = L + (size_t)(i0 + r) * NN;
    short* LbRow = Lb + (size_t)(i0 + r) * NN;
    const float* X0 = x + (size_t)r * NN;
    const float* X1 = x + (size_t)(r + 16) * NN;

    f32x4_t aA0 = {0.f,0.f,0.f,0.f}, aA1 = {0.f,0.f,0.f,0.f};
    f32x4_t aB0 = {0.f,0.f,0.f,0.f}, aB1 = {0.f,0.f,0.f,0.f};

#pragma unroll 2
    for (int it = 0; it < 16; ++it) {
        const int ja = jb + it * 32;
        const int jz = ja + 512;
        // stream A
        float4 la0 = *(const float4*)(Lrow + ja), la1 = *(const float4*)(Lrow + ja + 4);
        float4 xa00 = *(const float4*)(X0 + ja),  xa01 = *(const float4*)(X0 + ja + 4);
        float4 xa10 = *(const float4*)(X1 + ja),  xa11 = *(const float4*)(X1 + ja + 4);
        // stream B
        float4 lb0 = *(const float4*)(Lrow + jz), lb1 = *(const float4*)(Lrow + jz + 4);
        float4 xb00 = *(const float4*)(X0 + jz),  xb01 = *(const float4*)(X0 + jz + 4);
        float4 xb10 = *(const float4*)(X1 + jz),  xb11 = *(const float4*)(X1 + jz + 4);

        bf16x8_t bA = cvt8(la0, la1);
        bf16x8_t bB = cvt8(lb0, lb1);
        *(bf16x8_t*)(LbRow + ja) = bA;
        *(bf16x8_t*)(LbRow + jz) = bB;
        aA0 = __builtin_amdgcn_mfma_f32_16x16x32_bf16(cvt8(xa00, xa01), bA, aA0, 0, 0, 0);
        aA1 = __builtin_amdgcn_mfma_f32_16x16x32_bf16(cvt8(xa10, xa11), bA, aA1, 0, 0, 0);
        aB0 = __builtin_amdgcn_mfma_f32_16x16x32_bf16(cvt8(xb00, xb01), bB, aB0, 0, 0, 0);
        aB1 = __builtin_amdgcn_mfma_f32_16x16x32_bf16(cvt8(xb10, xb11), bB, aB1, 0, 0, 0);
    }

    f32x4_t s0, s1;
#pragma unroll
    for (int t = 0; t < 4; ++t) { s0[t] = aA0[t] + aB0[t]; s1[t] = aA1[t] + aB1[t]; }
    stash_partials(red, wave, g, r, s0, s1);
    __syncthreads();
    const int c = tid >> 4, il = tid & 15;
    const float val = reduce8(red, tid);
    const size_t off = (size_t)c * NN + i0 + il;
    Tf1[off] = val;
    Tb1[off] = f2bf(val);
}

// ---- Mid passes (2,3): T_next = 2*(Tcur @ L^T) - Tprev; bf16 Lb, dual K-stream.
__global__ __launch_bounds__(512, 4) void passmid_kernel(
    const short* __restrict__ Lb, const short* __restrict__ A,
    const float* __restrict__ Tprev, float* __restrict__ Tf, short* __restrict__ Tb)
{
    __shared__ float red[8 * 512];
    const int tid = threadIdx.x, wave = tid >> 6, lane = tid & 63;
    const int g = lane >> 4, r = lane & 15;
    const int i0 = blockIdx.x * 16;
    const int jb = wave * 1024 + g * 8;

    const short* Lrow = Lb + (size_t)(i0 + r) * NN;
    const short* A0 = A + (size_t)r * NN;
    const short* A1 = A + (size_t)(r + 16) * NN;

    f32x4_t aA0 = {0.f,0.f,0.f,0.f}, aA1 = {0.f,0.f,0.f,0.f};
    f32x4_t aB0 = {0.f,0.f,0.f,0.f}, aB1 = {0.f,0.f,0.f,0.f};

#pragma unroll 4
    for (int it = 0; it < 16; ++it) {
        const int ja = jb + it * 32;
        const int jz = ja + 512;
        bf16x8_t bA  = *(const bf16x8_t*)(Lrow + ja);
        bf16x8_t vA0 = *(const bf16x8_t*)(A0 + ja);
        bf16x8_t vA1 = *(const bf16x8_t*)(A1 + ja);
        bf16x8_t bB  = *(const bf16x8_t*)(Lrow + jz);
        bf16x8_t vB0 = *(const bf16x8_t*)(A0 + jz);
        bf16x8_t vB1 = *(const bf16x8_t*)(A1 + jz);
        aA0 = __builtin_amdgcn_mfma_f32_16x16x32_bf16(vA0, bA, aA0, 0, 0, 0);
        aA1 = __builtin_amdgcn_mfma_f32_16x16x32_bf16(vA1, bA, aA1, 0, 0, 0);
        aB0 = __builtin_amdgcn_mfma_f32_16x16x32_bf16(vB0, bB, aB0, 0, 0, 0);
        aB1 = __builtin_amdgcn_mfma_f32_16x16x32_bf16(vB1, bB, aB1, 0, 0, 0);
    }

    f32x4_t s0, s1;
#pragma unroll
    for (int t = 0; t < 4; ++t) { s0[t] = aA0[t] + aB0[t]; s1[t] = aA1[t] + aB1[t]; }
    stash_partials(red, wave, g, r, s0, s1);
    __syncthreads();
    const int c = tid >> 4, il = tid & 15;
    const float val = 2.0f * reduce8(red, tid) - Tprev[(size_t)c * NN + i0 + il];
    const size_t off = (size_t)c * NN + i0 + il;
    Tf[off] = val;
    Tb[off] = f2bf(val);
}

// ---- Pass 4 + fused final einsum (T4 stays in LDS):
__global__ __launch_bounds__(512, 4) void pass4_kernel(
    const short* __restrict__ Lb, const short* __restrict__ A,
    const float* __restrict__ Tf2, const float* __restrict__ x,
    const float* __restrict__ Tf1, const float* __restrict__ Tf3,
    const float* __restrict__ theta, const float* __restrict__ bias,
    float* __restrict__ y)
{
    __shared__ float red[8 * 512];              // partials, then T4[c][i]
    __shared__ float thS[COUT * CIN * KF];      // 40 KB
    const int tid = threadIdx.x, wave = tid >> 6, lane = tid & 63;
    const int g = lane >> 4, r = lane & 15;
    const int i0 = blockIdx.x * 16;
    const int jb = wave * 1024 + g * 8;

    const short* Lrow = Lb + (size_t)(i0 + r) * NN;
    const short* A0 = A + (size_t)r * NN;
    const short* A1 = A + (size_t)(r + 16) * NN;

    f32x4_t aA0 = {0.f,0.f,0.f,0.f}, aA1 = {0.f,0.f,0.f,0.f};
    f32x4_t aB0 = {0.f,0.f,0.f,0.f}, aB1 = {0.f,0.f,0.f,0.f};

#pragma unroll 4
    for (int it = 0; it < 16; ++it) {
        const int ja = jb + it * 32;
        const int jz = ja + 512;
        bf16x8_t bA  = *(const bf16x8_t*)(Lrow + ja);
        bf16x8_t vA0 = *(const bf16x8_t*)(A0 + ja);
        bf16x8_t vA1 = *(const bf16x8_t*)(A1 + ja);
        bf16x8_t bB  = *(const bf16x8_t*)(Lrow + jz);
        bf16x8_t vB0 = *(const bf16x8_t*)(A0 + jz);
        bf16x8_t vB1 = *(const bf16x8_t*)(A1 + jz);
        aA0 = __builtin_amdgcn_mfma_f32_16x16x32_bf16(vA0, bA, aA0, 0, 0, 0);
        aA1 = __builtin_amdgcn_mfma_f32_16x16x32_bf16(vA1, bA, aA1, 0, 0, 0);
        aB0 = __builtin_amdgcn_mfma_f32_16x16x32_bf16(vB0, bB, aB0, 0, 0, 0);
        aB1 = __builtin_amdgcn_mfma_f32_16x16x32_bf16(vB1, bB, aB1, 0, 0, 0);
    }

    f32x4_t s0, s1;
#pragma unroll
    for (int t = 0; t < 4; ++t) { s0[t] = aA0[t] + aB0[t]; s1[t] = aA1[t] + aB1[t]; }
    stash_partials(red, wave, g, r, s0, s1);
    __syncthreads();

    // T4 column for this thread -> red[tid] (own-slot overwrite, safe pre-barrier)
    {
        const int c = tid >> 4, il = tid & 15;
        red[tid] = 2.0f * reduce8(red, tid) - Tf2[(size_t)c * NN + i0 + il];
    }
    for (int t = tid; t < COUT * CIN * KF; t += 512) thS[t] = theta[t];
    __syncthreads();

    // einsum: thread -> (o=tid>>4, o+32) x column (i0 + il)
    const int o = tid >> 4, il = tid & 15;
    float a0 = bias[o], a1 = bias[o + 32];
    for (int cc = 0; cc < CIN; ++cc) {
        const size_t off = (size_t)cc * NN + i0 + il;
        const float t0 = x[off], t1 = Tf1[off], t2 = Tf2[off], t3 = Tf3[off];
        const float t4 = red[cc * 16 + il];
        const float* th0 = &thS[(o * CIN + cc) * KF];
        const float* th1 = &thS[((o + 32) * CIN + cc) * KF];
        a0 += t0 * th0[0] + t1 * th0[1] + t2 * th0[2] + t3 * th0[3] + t4 * th0[4];
        a1 += t0 * th1[0] + t1 * th1[1] + t2 * th1[2] + t3 * th1[3] + t4 * th1[4];
    }
    y[(size_t)o * NN + i0 + il]        = a0;
    y[(size_t)(o + 32) * NN + i0 + il] = a1;
}

extern "C" void kernel_launch(void* const* d_in, const int* in_sizes, int n_in,
                              void* d_out, int out_size, void* d_ws, size_t ws_size,
                              hipStream_t stream) {
    const float* L     = (const float*)d_in[0];
    const float* x     = (const float*)d_in[1];
    const float* theta = (const float*)d_in[2];
    const float* bias  = (const float*)d_in[3];
    float* y = (float*)d_out;

    const size_t TE = (size_t)CIN * NN;
    const size_t LE = (size_t)NN * NN;

    // ws: Lb(128MB) | Tf1..Tf3 (1MB ea) | Tb1..Tb3 (0.5MB ea)
    short* Lb  = (short*)d_ws;
    float* Tf1 = (float*)(Lb + LE);
    float* Tf2 = Tf1 + TE;
    float* Tf3 = Tf2 + TE;
    short* Tb1 = (short*)(Tf3 + TE);
    short* Tb2 = Tb1 + TE;
    short* Tb3 = Tb2 + TE;

    pass1_kernel<<<NN / 16, 512, 0, stream>>>(L, x, Lb, Tf1, Tb1);
    passmid_kernel<<<NN / 16, 512, 0, stream>>>(Lb, Tb1, x,   Tf2, Tb2);  // T2
    passmid_kernel<<<NN / 16, 512, 0, stream>>>(Lb, Tb2, Tf1, Tf3, Tb3);  // T3
    pass4_kernel<<<NN / 16, 512, 0, stream>>>(Lb, Tb3, Tf2, x, Tf1, Tf3,
                                              theta, bias, y);            // T4 + einsum
}